// Round 1
// baseline (531.280 us; speedup 1.0000x reference)
//
#include <hip/hip_runtime.h>

#define NB 256      // batch
#define TT 200      // time steps
#define DD 1250     // input dim
#define H1 100
#define H2 20
#define NO 2

#define KC 25       // K-chunk
#define NCHUNK 50   // 1250 / 25
#define WPITCH 104  // w_s row pitch (dwords), 16B-aligned

__launch_bounds__(256, 1)
__global__ void rnn_fused(const float* __restrict__ x,
                          const float* __restrict__ Wih1,
                          const float* __restrict__ Whh1,
                          const float* __restrict__ bih1,
                          const float* __restrict__ bhh1,
                          const float* __restrict__ Wih2,
                          const float* __restrict__ Whh2,
                          const float* __restrict__ bih2,
                          const float* __restrict__ bhh2,
                          const float* __restrict__ Wfc,
                          const float* __restrict__ bfc,
                          const float* __restrict__ mask1,
                          const float* __restrict__ mask2,
                          float* __restrict__ out)
{
    __shared__ alignas(16) float pre1_s[TT * H1];     // 80000 B
    __shared__ alignas(16) float x_s[TT * KC];        // 20000 B
    __shared__ alignas(16) float w_s[KC * WPITCH];    // 10400 B
    __shared__ alignas(16) float h1_s[2][H1];
    __shared__ alignas(16) float o1_s[2][H1];
    __shared__ alignas(16) float h2_s[2][H2];
    __shared__ alignas(16) float h2f_s[H2];

    const int tid = threadIdx.x;
    const int b   = blockIdx.x;
    const float* xb  = x     + (size_t)b * TT * DD;
    const float* m1b = mask1 + (size_t)b * TT * H1;

    // ================= Phase 1: pre1 = x[b] @ W_ih1^T (fp32, in-LDS) ==========
    // 250 active threads: hgrp = tid%25 -> 4 h-cols, tgrp = tid/25 -> 4 t-rows
    // per pass p (5 passes of 40 t). acc fully register-resident across chunks.
    const int hgrp = tid % 25;
    const int tgrp = tid / 25;
    const bool act = (tgrp < 10);

    float acc[5][4][4];
    #pragma unroll
    for (int p = 0; p < 5; ++p)
        #pragma unroll
        for (int r = 0; r < 4; ++r)
            #pragma unroll
            for (int c = 0; c < 4; ++c)
                acc[p][r][c] = 0.f;

    // register-double-buffered staging (issue-early / write-late)
    float xr[20], wr[10];
    #pragma unroll
    for (int q = 0; q < 20; ++q) {
        int idx = tid + q * 256;
        if (idx < TT * KC) xr[q] = xb[(idx / KC) * DD + (idx % KC)];
    }
    #pragma unroll
    for (int q = 0; q < 10; ++q) {
        int idx = tid + q * 256;
        if (idx < H1 * KC) wr[q] = Wih1[(idx / KC) * DD + (idx % KC)];
    }

    for (int kc = 0; kc < NCHUNK; ++kc) {
        // write staged regs -> LDS
        #pragma unroll
        for (int q = 0; q < 20; ++q) {
            int idx = tid + q * 256;
            if (idx < TT * KC) x_s[idx] = xr[q];               // identity layout
        }
        #pragma unroll
        for (int q = 0; q < 10; ++q) {
            int idx = tid + q * 256;
            if (idx < H1 * KC) w_s[(idx % KC) * WPITCH + (idx / KC)] = wr[q];
        }
        __syncthreads();

        // issue next chunk's global loads (latency hides under compute)
        if (kc + 1 < NCHUNK) {
            const int kb = (kc + 1) * KC;
            #pragma unroll
            for (int q = 0; q < 20; ++q) {
                int idx = tid + q * 256;
                if (idx < TT * KC) xr[q] = xb[(idx / KC) * DD + kb + (idx % KC)];
            }
            #pragma unroll
            for (int q = 0; q < 10; ++q) {
                int idx = tid + q * 256;
                if (idx < H1 * KC) wr[q] = Wih1[(idx / KC) * DD + kb + (idx % KC)];
            }
        }

        if (act) {
            #pragma unroll 5
            for (int kk = 0; kk < KC; ++kk) {
                const float4 wv = *(const float4*)&w_s[kk * WPITCH + 4 * hgrp];
                #pragma unroll
                for (int p = 0; p < 5; ++p) {
                    #pragma unroll
                    for (int r = 0; r < 4; ++r) {
                        const float xv = x_s[(p * 40 + tgrp * 4 + r) * KC + kk];
                        acc[p][r][0] = fmaf(xv, wv.x, acc[p][r][0]);
                        acc[p][r][1] = fmaf(xv, wv.y, acc[p][r][1]);
                        acc[p][r][2] = fmaf(xv, wv.z, acc[p][r][2]);
                        acc[p][r][3] = fmaf(xv, wv.w, acc[p][r][3]);
                    }
                }
            }
        }
        __syncthreads();
    }

    // flush accumulators -> pre1_s (one-time)
    if (act) {
        #pragma unroll
        for (int p = 0; p < 5; ++p)
            #pragma unroll
            for (int r = 0; r < 4; ++r) {
                const int t = p * 40 + tgrp * 4 + r;
                float4 v = make_float4(acc[p][r][0], acc[p][r][1],
                                       acc[p][r][2], acc[p][r][3]);
                *(float4*)&pre1_s[t * H1 + 4 * hgrp] = v;
            }
    }

    // ============== load per-thread weight rows into registers ===============
    float w1r[H1];
    float b1 = 0.f;
    if (tid < H1) {
        #pragma unroll
        for (int jq = 0; jq < H1 / 4; ++jq) {
            float4 v = *(const float4*)&Whh1[tid * H1 + 4 * jq];
            w1r[4 * jq + 0] = v.x; w1r[4 * jq + 1] = v.y;
            w1r[4 * jq + 2] = v.z; w1r[4 * jq + 3] = v.w;
        }
        b1 = bih1[tid] + bhh1[tid];
    }
    float wi2r[H1], wh2r[H2];
    float b2 = 0.f;
    const bool l2t = (tid >= 128 && tid < 128 + H2);
    const int  k2  = tid - 128;
    if (l2t) {
        #pragma unroll
        for (int iq = 0; iq < H1 / 4; ++iq) {
            float4 v = *(const float4*)&Wih2[k2 * H1 + 4 * iq];
            wi2r[4 * iq + 0] = v.x; wi2r[4 * iq + 1] = v.y;
            wi2r[4 * iq + 2] = v.z; wi2r[4 * iq + 3] = v.w;
        }
        #pragma unroll
        for (int lq = 0; lq < H2 / 4; ++lq) {
            float4 v = *(const float4*)&Whh2[k2 * H2 + 4 * lq];
            wh2r[4 * lq + 0] = v.x; wh2r[4 * lq + 1] = v.y;
            wh2r[4 * lq + 2] = v.z; wh2r[4 * lq + 3] = v.w;
        }
        b2 = bih2[k2] + bhh2[k2];
    }

    // init recurrent state
    if (tid < H1) { h1_s[0][tid] = 0.f; h1_s[1][tid] = 0.f;
                    o1_s[0][tid] = 0.f; o1_s[1][tid] = 0.f; }
    if (tid < H2) { h2_s[0][tid] = 0.f; h2_s[1][tid] = 0.f; }
    __syncthreads();

    // ================= Phase 2: fused two-layer scan =========================
    // layer1 on threads 0..99 computes h1(t); layer2 on threads 128..147
    // computes h2(t-1) (one step behind, different wave -> pipelined).
    for (int t = 0; t <= TT; ++t) {
        const int cur = t & 1, nxt = cur ^ 1;
        float h1new = 0.f, o1new = 0.f, h2new = 0.f;

        if (tid < H1 && t < TT) {
            const float mv = m1b[t * H1 + tid];        // issued early
            float a0 = pre1_s[t * H1 + tid] + b1;
            float a1 = 0.f, a2 = 0.f, a3 = 0.f;
            const float4* h4 = (const float4*)&h1_s[cur][0];
            #pragma unroll
            for (int jq = 0; jq < H1 / 4; ++jq) {
                const float4 hv = h4[jq];              // broadcast read
                a0 = fmaf(w1r[4 * jq + 0], hv.x, a0);
                a1 = fmaf(w1r[4 * jq + 1], hv.y, a1);
                a2 = fmaf(w1r[4 * jq + 2], hv.z, a2);
                a3 = fmaf(w1r[4 * jq + 3], hv.w, a3);
            }
            h1new = fmaxf((a0 + a1) + (a2 + a3), 0.f);
            o1new = h1new * mv;
        }

        if (l2t && t >= 1) {
            float a0 = b2, a1 = 0.f, a2 = 0.f, a3 = 0.f;
            const float4* o4 = (const float4*)&o1_s[cur][0];   // o1(t-1)
            #pragma unroll
            for (int iq = 0; iq < H1 / 4; ++iq) {
                const float4 ov = o4[iq];
                a0 = fmaf(wi2r[4 * iq + 0], ov.x, a0);
                a1 = fmaf(wi2r[4 * iq + 1], ov.y, a1);
                a2 = fmaf(wi2r[4 * iq + 2], ov.z, a2);
                a3 = fmaf(wi2r[4 * iq + 3], ov.w, a3);
            }
            const float4* g4 = (const float4*)&h2_s[cur][0];   // h2(t-2)
            #pragma unroll
            for (int lq = 0; lq < H2 / 4; ++lq) {
                const float4 gv = g4[lq];
                a0 = fmaf(wh2r[4 * lq + 0], gv.x, a0);
                a1 = fmaf(wh2r[4 * lq + 1], gv.y, a1);
                a2 = fmaf(wh2r[4 * lq + 2], gv.z, a2);
                a3 = fmaf(wh2r[4 * lq + 3], gv.w, a3);
            }
            h2new = fmaxf((a0 + a1) + (a2 + a3), 0.f);
        }

        // publish to the other buffer (no hazard with this iteration's reads)
        if (tid < H1 && t < TT) { h1_s[nxt][tid] = h1new; o1_s[nxt][tid] = o1new; }
        if (l2t && t >= 1) {
            h2_s[nxt][k2] = h2new;
            if (t == TT) h2f_s[k2] = h2new;            // h2(199)
        }
        __syncthreads();
    }

    // ================= FC on last step ======================================
    if (tid < NO) {
        const float* m2 = mask2 + ((size_t)b * TT + (TT - 1)) * H2;
        float s = bfc[tid];
        #pragma unroll
        for (int k = 0; k < H2; ++k)
            s = fmaf(Wfc[tid * H2 + k], h2f_s[k] * m2[k], s);
        out[b * NO + tid] = s;
    }
}

extern "C" void kernel_launch(void* const* d_in, const int* in_sizes, int n_in,
                              void* d_out, int out_size, void* d_ws, size_t ws_size,
                              hipStream_t stream) {
    rnn_fused<<<dim3(NB), dim3(256), 0, stream>>>(
        (const float*)d_in[0],  (const float*)d_in[1],  (const float*)d_in[2],
        (const float*)d_in[3],  (const float*)d_in[4],  (const float*)d_in[5],
        (const float*)d_in[6],  (const float*)d_in[7],  (const float*)d_in[8],
        (const float*)d_in[9],  (const float*)d_in[10], (const float*)d_in[11],
        (const float*)d_in[12], (float*)d_out);
}